// Round 2
// baseline (12720.228 us; speedup 1.0000x reference)
//
#include <hip/hip_runtime.h>
#include <hip/hip_bf16.h>

// JANET layer: T=2048, B=64, I=256, H=256.
// Phase 1: xfh[row][0:256] = seq_row @ W_f + b_f ; xfh[row][256:512] = seq_row @ W_h + b_h
// Phase 2: per-batch recurrence. Thread pair (2j,2j+1) owns hidden column j:
//   each lane holds a 128-row k-half of U_f[:,j] and U_h[:,j] in regs (AGPR-parked),
//   one shfl_xor(1) per gate to combine, one barrier per step, h double-buffered in LDS,
//   x prefetched 4 steps ahead.

#define T_STEPS 2048
#define BATCH   64
#define NCOL    512

__device__ __forceinline__ float4 ld4(const float* p) { return *(const float4*)p; }
__device__ __forceinline__ void fma4(float4& acc, float s, const float4& v) {
  acc.x = fmaf(s, v.x, acc.x); acc.y = fmaf(s, v.y, acc.y);
  acc.z = fmaf(s, v.z, acc.z); acc.w = fmaf(s, v.w, acc.w);
}

__device__ __forceinline__ void store_xt(float* p, const float4& v) { *(float4*)p = v; }
__device__ __forceinline__ void store_xt(__hip_bfloat16* p, const float4& v) {
  p[0] = __float2bfloat16(v.x); p[1] = __float2bfloat16(v.y);
  p[2] = __float2bfloat16(v.z); p[3] = __float2bfloat16(v.w);
}
__device__ __forceinline__ float xload(const float* p) { return *p; }
__device__ __forceinline__ float xload(const __hip_bfloat16* p) { return __bfloat162float(*p); }

// ---------------- Phase 1: input-projection GEMM (unchanged from R1) ----------------
template <typename XT>
__global__ __launch_bounds__(256, 4)
void xproj_gemm(const float* __restrict__ seq,
                const float* __restrict__ Wf, const float* __restrict__ bf,
                const float* __restrict__ Wh, const float* __restrict__ bh,
                XT* __restrict__ xfh)
{
  __shared__ float As[32 * 132];   // A^T: [k][m], pitch 132
  __shared__ float Bs[32 * 132];   // B:   [k][n], pitch 132
  const int tid = threadIdx.x;
  const int mt = blockIdx.x >> 2;
  const int nt = blockIdx.x & 3;
  const int m0 = mt * 128;
  const int n0 = nt * 128;
  const int tm = tid >> 4;
  const int tn = tid & 15;

  float4 acc[8][2];
  #pragma unroll
  for (int i = 0; i < 8; ++i) {
    acc[i][0] = make_float4(0.f, 0.f, 0.f, 0.f);
    acc[i][1] = make_float4(0.f, 0.f, 0.f, 0.f);
  }

  const float* bsrc  = (n0 < 256) ? Wf : Wh;
  const int    bcol0 = (n0 < 256) ? n0 : (n0 - 256);

  for (int kt = 0; kt < 8; ++kt) {
    const int k0 = kt * 32;
    #pragma unroll
    for (int p = 0; p < 4; ++p) {
      int idx = p * 256 + tid;
      int r   = idx >> 3;
      int c4  = idx & 7;
      float4 v = ld4(seq + (size_t)(m0 + r) * 256 + k0 + c4 * 4);
      As[(c4*4+0)*132 + r] = v.x;
      As[(c4*4+1)*132 + r] = v.y;
      As[(c4*4+2)*132 + r] = v.z;
      As[(c4*4+3)*132 + r] = v.w;
    }
    #pragma unroll
    for (int p = 0; p < 4; ++p) {
      int idx = p * 256 + tid;
      int kr  = idx >> 5;
      int c4  = idx & 31;
      float4 v = ld4(bsrc + (size_t)(k0 + kr) * 256 + bcol0 + c4 * 4);
      *(float4*)&Bs[kr*132 + c4*4] = v;
    }
    __syncthreads();
    #pragma unroll
    for (int k = 0; k < 32; ++k) {
      float4 a0 = ld4(&As[k*132 + tm*4]);
      float4 a1 = ld4(&As[k*132 + 64 + tm*4]);
      float4 b0 = ld4(&Bs[k*132 + tn*4]);
      float4 b1 = ld4(&Bs[k*132 + 64 + tn*4]);
      float ar[8] = {a0.x, a0.y, a0.z, a0.w, a1.x, a1.y, a1.z, a1.w};
      #pragma unroll
      for (int i = 0; i < 8; ++i) {
        fma4(acc[i][0], ar[i], b0);
        fma4(acc[i][1], ar[i], b1);
      }
    }
    __syncthreads();
  }

  const float* bias_src = (n0 < 256) ? bf : bh;
  float4 bias0 = ld4(bias_src + bcol0 + tn*4);
  float4 bias1 = ld4(bias_src + bcol0 + 64 + tn*4);
  #pragma unroll
  for (int i = 0; i < 8; ++i) {
    int m = m0 + ((i < 4) ? (tm*4 + i) : (64 + tm*4 + (i - 4)));
    float4 r0 = acc[i][0];
    r0.x += bias0.x; r0.y += bias0.y; r0.z += bias0.z; r0.w += bias0.w;
    float4 r1 = acc[i][1];
    r1.x += bias1.x; r1.y += bias1.y; r1.z += bias1.z; r1.w += bias1.w;
    store_xt(xfh + (size_t)m * NCOL + n0 + tn*4,      r0);
    store_xt(xfh + (size_t)m * NCOL + n0 + 64 + tn*4, r1);
  }
}

// ---------------- Phase 2: sequential recurrence ----------------
template <typename XT>
__global__ __launch_bounds__(512, 2)
void janet_rec(const float* __restrict__ Uf, const float* __restrict__ Uh,
               const XT* __restrict__ xfh, const float* __restrict__ pa,
               float* __restrict__ out)
{
  __shared__ float h_lds[2][256];
  const int tid  = threadIdx.x;
  const int b    = blockIdx.x;
  const int j    = tid >> 1;     // hidden column 0..255
  const int half = tid & 1;      // k-half
  const int k0   = half * 128;

  // Per-thread U slices: uf[c] = U_f[k0+4c .. k0+4c+3][j], likewise uh.
  float4 uf[32], uh[32];
  #pragma unroll
  for (int c = 0; c < 32; ++c) {
    const int k = k0 + c * 4;
    uf[c] = make_float4(Uf[(size_t)(k+0)*256 + j], Uf[(size_t)(k+1)*256 + j],
                        Uf[(size_t)(k+2)*256 + j], Uf[(size_t)(k+3)*256 + j]);
    uh[c] = make_float4(Uh[(size_t)(k+0)*256 + j], Uh[(size_t)(k+1)*256 + j],
                        Uh[(size_t)(k+2)*256 + j], Uh[(size_t)(k+3)*256 + j]);
  }
  const float aprelu = pa[0];

  if (tid < 256) { h_lds[0][tid] = 0.f; }
  float h_old = 0.f;

  // x prefetch queue, 4 deep
  float xf_q[4], xh_q[4];
  #pragma unroll
  for (int i = 0; i < 4; ++i) {
    const size_t row = (size_t)i * BATCH + b;
    xf_q[i] = xload(xfh + row * NCOL + j);
    xh_q[i] = xload(xfh + row * NCOL + 256 + j);
  }
  __syncthreads();

  for (int t4 = 0; t4 < T_STEPS; t4 += 4) {
    #pragma unroll
    for (int i = 0; i < 4; ++i) {
      const int t = t4 + i;
      const float xf_cur = xf_q[i];
      const float xh_cur = xh_q[i];
      // prefetch t+4 (clamped; clamped values are never consumed)
      {
        int tp = t + 4; if (tp > T_STEPS - 1) tp = T_STEPS - 1;
        const size_t row = (size_t)tp * BATCH + b;
        xf_q[i] = xload(xfh + row * NCOL + j);
        xh_q[i] = xload(xfh + row * NCOL + 256 + j);
      }

      const int rb = t & 1;
      // matvec partials over this lane's k-half (4 chains for ILP)
      float4 accf = make_float4(0.f, 0.f, 0.f, 0.f);
      float4 accg = make_float4(0.f, 0.f, 0.f, 0.f);
      const float4* h4 = (const float4*)&h_lds[rb][k0];
      #pragma unroll
      for (int c = 0; c < 32; c += 2) {
        float4 h0 = h4[c];
        float4 h1 = h4[c + 1];
        accf.x = fmaf(h0.x, uf[c].x, accf.x);
        accf.y = fmaf(h0.y, uf[c].y, accf.y);
        accf.z = fmaf(h0.z, uf[c].z, accf.z);
        accf.w = fmaf(h0.w, uf[c].w, accf.w);
        accg.x = fmaf(h0.x, uh[c].x, accg.x);
        accg.y = fmaf(h0.y, uh[c].y, accg.y);
        accg.z = fmaf(h0.z, uh[c].z, accg.z);
        accg.w = fmaf(h0.w, uh[c].w, accg.w);
        accf.x = fmaf(h1.x, uf[c+1].x, accf.x);
        accf.y = fmaf(h1.y, uf[c+1].y, accf.y);
        accf.z = fmaf(h1.z, uf[c+1].z, accf.z);
        accf.w = fmaf(h1.w, uf[c+1].w, accf.w);
        accg.x = fmaf(h1.x, uh[c+1].x, accg.x);
        accg.y = fmaf(h1.y, uh[c+1].y, accg.y);
        accg.z = fmaf(h1.z, uh[c+1].z, accg.z);
        accg.w = fmaf(h1.w, uh[c+1].w, accg.w);
      }
      float pf = (accf.x + accf.y) + (accf.z + accf.w);
      float pg = (accg.x + accg.y) + (accg.z + accg.w);
      // combine k-halves across the lane pair (single level, in-wave)
      pf += __shfl_xor(pf, 1);
      pg += __shfl_xor(pg, 1);

      const float pre_f = pf + xf_cur;
      const float pre_g = pg + xh_cur;
      const float f = __builtin_amdgcn_rcpf(1.f + __expf(-pre_f));   // sigmoid
      const float e2 = __expf(2.f * pre_g);
      const float g  = 1.f - 2.f * __builtin_amdgcn_rcpf(e2 + 1.f);  // tanh
      float hn = fmaf(f, h_old - g, g);          // f*h + (1-f)*g
      hn = (hn >= 0.f) ? hn : aprelu * hn;       // prelu
      h_old = hn;                                // both lanes keep it

      if (half == 0) {
        h_lds[rb ^ 1][j] = hn;                   // publish to the other buffer
      } else {
        out[((size_t)t * BATCH + b) * 256 + j] = hn;
      }
      __syncthreads();                           // one barrier per step
    }
  }
}

extern "C" void kernel_launch(void* const* d_in, const int* in_sizes, int n_in,
                              void* d_out, int out_size, void* d_ws, size_t ws_size,
                              hipStream_t stream) {
  const float* seq = (const float*)d_in[0];
  const float* Wf  = (const float*)d_in[1];
  const float* Uf  = (const float*)d_in[2];
  const float* bf  = (const float*)d_in[3];
  const float* Wh  = (const float*)d_in[4];
  const float* Uh  = (const float*)d_in[5];
  const float* bh  = (const float*)d_in[6];
  const float* pa  = (const float*)d_in[7];
  float* out = (float*)d_out;

  const size_t rows = (size_t)T_STEPS * BATCH;
  const size_t need_f32 = rows * NCOL * sizeof(float);   // 256 MiB

  dim3 g1(4096), blk1(256);
  dim3 g2(BATCH), blk2(512);

  if (ws_size >= need_f32) {
    float* xfh = (float*)d_ws;
    hipLaunchKernelGGL(xproj_gemm<float>, g1, blk1, 0, stream, seq, Wf, bf, Wh, bh, xfh);
    hipLaunchKernelGGL(janet_rec<float>,  g2, blk2, 0, stream, Uf, Uh, xfh, pa, out);
  } else {
    __hip_bfloat16* xfh = (__hip_bfloat16*)d_ws;
    hipLaunchKernelGGL(xproj_gemm<__hip_bfloat16>, g1, blk1, 0, stream, seq, Wf, bf, Wh, bh, xfh);
    hipLaunchKernelGGL(janet_rec<__hip_bfloat16>,  g2, blk2, 0, stream, Uf, Uh, xfh, pa, out);
  }
}